// Round 12
// baseline (586.323 us; speedup 1.0000x reference)
//
#include <hip/hip_runtime.h>

typedef unsigned short u16;
typedef unsigned int   u32;
typedef _Float16 f16;
typedef __attribute__((ext_vector_type(8))) _Float16 half8;
typedef __attribute__((ext_vector_type(4))) float f32x4;

#define NBATCH 16384

__device__ __forceinline__ u16 f2h(float x) {
  union { f16 h; u16 u; } v; v.h = (f16)x; return v.u;
}

// ---------- prep: transpose fp32 (M x N) -> f16 (N x M), 16 mats (z = layer*2 + net)
// Single launch; blockIdx.x segments: [0,16) W1 | [16,272) W2 | [272,288) W3.
__global__ __launch_bounds__(256) void cvt_all(
    const float* __restrict__ tW1, const float* __restrict__ sW1,
    const float* __restrict__ tW2, const float* __restrict__ sW2,
    const float* __restrict__ tW3, const float* __restrict__ sW3,
    u16* __restrict__ dW1, u16* __restrict__ dW2, u16* __restrict__ dW3)
{
  __shared__ float tile[32][33];
  const int z = blockIdx.z, bx = blockIdx.x;
  const float *tsrc, *ssrc; u16* dst; int M, N, nt, mt;
  if (bx < 16)       { tsrc = tW1; ssrc = sW1; dst = dW1; M = 32;  N = 512; nt = bx;           mt = 0; }
  else if (bx < 272) { tsrc = tW2; ssrc = sW2; dst = dW2; M = 512; N = 512; nt = (bx - 16) & 15; mt = (bx - 16) >> 4; }
  else               { tsrc = tW3; ssrc = sW3; dst = dW3; M = 512; N = 32;  nt = 0;            mt = bx - 272; }
  const float* src = ((z & 1) ? ssrc : tsrc) + (size_t)(z >> 1) * M * N;
  u16* d = dst + (size_t)z * M * N;
  const int n0 = nt * 32, m0 = mt * 32;
  for (int r = 0; r < 4; r++) {
    int m = m0 + threadIdx.y + r * 8, n = n0 + threadIdx.x;
    tile[threadIdx.y + r * 8][threadIdx.x] = src[(size_t)m * N + n];
  }
  __syncthreads();
  for (int r = 0; r < 4; r++) {
    int n = n0 + threadIdx.y + r * 8, m = m0 + threadIdx.x;
    d[(size_t)n * M + m] = f2h(tile[threadIdx.x][threadIdx.y + r * 8]);
  }
}

// ---------- fused RealNVP: 1 block = 64 rows, 1024 threads, 16 waves, 256 blocks.
// R12: NET-PARALLEL wave groups. R10/R11 proved occupancy alone is null — the
// limiter is the serialized phase chain H1(t)->H2(t)->head(t)->H1(s)->... .
// The t/s nets are independent given X, so: group w>>3 computes net t or s
// CONCURRENTLY. Each wave keeps R10's exact shape (64 cols, acc[4][4],
// bb[3][4] depth-3, av ping-pong — measured 120 VGPR, fits the 128 cap of a
// 1024-thread block). One in-place 64KB H-buffer per net (R0-proven pattern):
// bufT + bufS + X + TS = 150 KB. Per-layer critical path: ONE net-pass, 5
// barriers (was 2 passes, 7). W2/L2, LDS, MFMA totals per CU unchanged.
__global__ __launch_bounds__(1024, 1) void meganvp(
    const float* __restrict__ y,
    const u16* __restrict__ W1T, const u16* __restrict__ W2T, const u16* __restrict__ W3T,
    const float* __restrict__ tb1, const float* __restrict__ sb1,
    const float* __restrict__ tb2, const float* __restrict__ sb2,
    const float* __restrict__ tb3, const float* __restrict__ sb3,
    const float* __restrict__ s_scale, const float* __restrict__ s_shift,
    float* __restrict__ out)
{
  __shared__ u16 bufT[64 * 512];    // 64 KB: t-net H1/H2 in place (XOR-swizzled)
  __shared__ u16 bufS[64 * 512];    // 64 KB: s-net H1/H2 in place
  __shared__ u16 X[64 * 40];        // 5 KB: f16 pass-through half
  __shared__ float TS[64 * 68];     // 17 KB: coupling (t,s) pairs, 16B-aligned rows

  const int t = threadIdx.x;
  const int m0 = blockIdx.x * 64;
  const int lane = t & 63, w = t >> 6, lm = lane & 15, quad = lane >> 4;
  const int net = w >> 3, wg = w & 7;          // wave group = net; wg in group
  const int cw = wg * 64;                      // wave's 64-col slice of its net
  const int phase = blockIdx.x & 15;
  const int zr = t >> 4, zc0 = (t & 15) * 4;   // z ownership: row zr, 4 cols
  u16* buf = net ? bufS : bufT;

  float z[4], ld[4];
  {
    const float* yb = y + (size_t)(m0 + zr) * 64 + zc0;
    f32x4 v = *(const f32x4*)yb;
#pragma unroll
    for (int k = 0; k < 4; k++) { z[k] = v[k]; ld[k] = 0.f; }
  }

  for (int layer = 0; layer < 8; layer++) {
    const int par = layer & 1;
    const int idx = layer * 2 + net;
    { // X build: 2 pass-through f16 per thread (R11-verified 1024-thread geom)
      union { u16 a[2]; u32 v; } xv;
      xv.a[0] = f2h(z[1 - par]);
      xv.a[1] = f2h(z[3 - par]);
      *(u32*)&X[zr * 40 + (zc0 >> 1)] = xv.v;
    }
    __syncthreads();                          // bar0: X visible; fences TS reads

    // ---- H1 = relu(X @ W1 + b1), K=32, wave cols [cw,+64) of ITS net -> buf
    // swapped mfma: lane holds H1[m = rt*16 + lm, n = cw + ct*16 + quad*4 + g]
    {
      const float* b1p = (net ? sb1 : tb1) + layer * 512 + cw + quad * 4;
      f32x4 bias1[4];
#pragma unroll
      for (int ct = 0; ct < 4; ct++) bias1[ct] = *(const f32x4*)&b1p[ct * 16];
      const u16* W1p = W1T + ((size_t)idx * 512 + cw + lm) * 32 + quad * 8;
      half8 bv[4];
#pragma unroll
      for (int ct = 0; ct < 4; ct++) bv[ct] = *(const half8*)&W1p[ct * 512];
      half8 av[4];
#pragma unroll
      for (int rt = 0; rt < 4; rt++)
        av[rt] = *(const half8*)&X[(rt * 16 + lm) * 40 + quad * 8];
      f32x4 acc[4][4];
#pragma unroll
      for (int rt = 0; rt < 4; rt++)
#pragma unroll
        for (int ct = 0; ct < 4; ct++)
          acc[rt][ct] = __builtin_amdgcn_mfma_f32_16x16x32_f16(bv[ct], av[rt], bias1[ct], 0, 0, 0);
      // buf is free: prev layer's head reads finished before its barrier
#pragma unroll
      for (int rt = 0; rt < 4; rt++) {
        const int m = rt * 16 + lm;
#pragma unroll
        for (int ct = 0; ct < 4; ct++) {
          const int n0 = cw + ct * 16 + quad * 4;
          union { u16 a[4]; uint2 v; } pk;
#pragma unroll
          for (int g = 0; g < 4; g++) {
            float v = acc[rt][ct][g];
            pk.a[g] = f2h(v > 0.f ? v : 0.f);
          }
          *(uint2*)&buf[m * 512 + ((((n0 >> 3) ^ (m & 7)) << 3) | (n0 & 7))] = pk.v;
        }
      }
    }
    __syncthreads();                          // bar1: H1 (both nets) written

    // ---- H2 = relu(H1 @ W2 + b2), K=512, depth-3 W2 prefetch, av ping-pong.
    // In-place: K-loop reads ALL of buf; epilogue write deferred past bar2.
    {
      const float* b2p = (net ? sb2 : tb2) + layer * 512 + cw + quad * 4;
      f32x4 acc[4][4];
#pragma unroll
      for (int ct = 0; ct < 4; ct++) {
        const f32x4 b = *(const f32x4*)&b2p[ct * 16];
#pragma unroll
        for (int rt = 0; rt < 4; rt++) acc[rt][ct] = b;
      }
      const u16* W2p = W2T + ((size_t)idx * 512 + cw + lm) * 512 + quad * 8;
      half8 bb[3][4];                         // depth-3 rotating prefetch
#pragma unroll
      for (int p = 0; p < 3; p++) {
        const int kp = ((p + phase) & 15) * 32;
#pragma unroll
        for (int ct = 0; ct < 4; ct++)
          bb[p][ct] = *(const half8*)&W2p[ct * 8192 + kp];
      }
      half8 av[2][4];                         // ping-pong A-frags
      {
        const int kk0 = (phase & 15) * 32;
#pragma unroll
        for (int rt = 0; rt < 4; rt++) {
          const int m = rt * 16 + lm;
          av[0][rt] = *(const half8*)&buf[m * 512 + ((((kk0 >> 3) + quad) ^ (m & 7)) << 3)];
        }
      }
#pragma unroll
      for (int ci = 0; ci < 16; ci++) {
        if (ci < 15) {                        // prefetch next iter's A-frags
          const int kk1 = ((ci + 1 + phase) & 15) * 32;
#pragma unroll
          for (int rt = 0; rt < 4; rt++) {
            const int m = rt * 16 + lm;
            av[(ci + 1) & 1][rt] = *(const half8*)&buf[m * 512 + ((((kk1 >> 3) + quad) ^ (m & 7)) << 3)];
          }
        }
#pragma unroll
        for (int rt = 0; rt < 4; rt++)
#pragma unroll
          for (int ct = 0; ct < 4; ct++)
            acc[rt][ct] = __builtin_amdgcn_mfma_f32_16x16x32_f16(bb[ci % 3][ct], av[ci & 1][rt], acc[rt][ct], 0, 0, 0);
        if (ci < 13) {                        // refill consumed W2 slot, 3 ahead
          const int kn = ((ci + 3 + phase) & 15) * 32;
#pragma unroll
          for (int ct = 0; ct < 4; ct++)
            bb[ci % 3][ct] = *(const half8*)&W2p[ct * 8192 + kn];
        }
      }
      __syncthreads();                        // bar2: all K-reads done -> in-place legal
#pragma unroll
      for (int rt = 0; rt < 4; rt++) {
        const int m = rt * 16 + lm;
#pragma unroll
        for (int ct = 0; ct < 4; ct++) {
          const int n0 = cw + ct * 16 + quad * 4;
          union { u16 a[4]; uint2 v; } pk;
#pragma unroll
          for (int g = 0; g < 4; g++) {
            float v = acc[rt][ct][g];
            pk.a[g] = f2h(v > 0.f ? v : 0.f);
          }
          *(uint2*)&buf[m * 512 + ((((n0 >> 3) ^ (m & 7)) << 3) | (n0 & 7))] = pk.v;
        }
      }
    }
    __syncthreads();                          // bar3: H2 (both nets) visible

    // ---- head: group's 8 waves -> rows [(wg&3)*16,+16), col tile (wg>>2)*16
    // swapped mfma: lane holds out[m = hr + lm, j = hc + quad*4 + g]
    {
      const int hr = (wg & 3) * 16, hc = (wg >> 2) * 16;
      const u16* W3p = W3T + ((size_t)idx * 32 + hc + lm) * 512 + quad * 8;
      const int j0 = hc + quad * 4;
      f32x4 ha[2];
      ha[0] = net ? *(const f32x4*)&sb3[layer * 32 + j0]
                  : *(const f32x4*)&tb3[layer * 32 + j0];
      ha[1] = (f32x4){0.f, 0.f, 0.f, 0.f};
      const int m = hr + lm;
      half8 pv[4];                            // depth-4 W3 prefetch
#pragma unroll
      for (int p = 0; p < 4; p++)
        pv[p] = *(const half8*)&W3p[((p + phase) & 15) * 32];
      half8 avh[2];
      {
        const int kk0 = (phase & 15) * 32;
        avh[0] = *(const half8*)&buf[m * 512 + ((((kk0 >> 3) + quad) ^ (m & 7)) << 3)];
      }
#pragma unroll
      for (int ci = 0; ci < 16; ci++) {
        if (ci < 15) {
          const int kk1 = ((ci + 1 + phase) & 15) * 32;
          avh[(ci + 1) & 1] = *(const half8*)&buf[m * 512 + ((((kk1 >> 3) + quad) ^ (m & 7)) << 3)];
        }
        ha[ci & 1] = __builtin_amdgcn_mfma_f32_16x16x32_f16(pv[ci & 3], avh[ci & 1], ha[ci & 1], 0, 0, 0);
        if (ci < 12)
          pv[ci & 3] = *(const half8*)&W3p[((ci + 4 + phase) & 15) * 32];
      }
      if (net == 0) {
#pragma unroll
        for (int g = 0; g < 4; g++)
          TS[m * 68 + 2 * (j0 + g)] = ha[0][g] + ha[1][g];
      } else {
        const f32x4 sc = *(const f32x4*)&s_scale[layer * 32 + j0];
        const f32x4 sh = *(const f32x4*)&s_shift[layer * 32 + j0];
#pragma unroll
        for (int g = 0; g < 4; g++)
          TS[m * 68 + 2 * (j0 + g) + 1] = tanhf(ha[0][g] + ha[1][g]) * sc[g] + sh[g];
      }
    }
    __syncthreads();                          // bar4: TS (both nets) complete

    // ---- coupling: thread reads its 2 (t,s) pairs, updates z/ld in registers.
    // (No trailing barrier: next bar0 orders these TS reads before next writes.)
    {
      f32x4 q = *(const f32x4*)&TS[zr * 68 + zc0];   // {t(j0), s(j0), t(j0+1), s(j0+1)}
      z[par]     = z[par]     * expf(q[1]) + q[0];  ld[par]     += q[1];
      z[2 + par] = z[2 + par] * expf(q[3]) + q[2];  ld[2 + par] += q[3];
    }
  } // layer

  // ---- store z and log_det
  {
    float* zb = out + (size_t)(m0 + zr) * 64 + zc0;
    float* lb = out + (size_t)NBATCH * 64 + (size_t)(m0 + zr) * 64 + zc0;
    f32x4 v0, l0;
#pragma unroll
    for (int k = 0; k < 4; k++) { v0[k] = z[k]; l0[k] = ld[k]; }
    *(f32x4*)zb = v0;
    *(f32x4*)lb = l0;
  }
}

extern "C" void kernel_launch(void* const* d_in, const int* in_sizes, int n_in,
                              void* d_out, int out_size, void* d_ws, size_t ws_size,
                              hipStream_t stream) {
  (void)in_sizes; (void)n_in; (void)out_size; (void)ws_size;
  const float* y   = (const float*)d_in[0];
  const float* tW1 = (const float*)d_in[1];
  const float* tb1 = (const float*)d_in[2];
  const float* tW2 = (const float*)d_in[3];
  const float* tb2 = (const float*)d_in[4];
  const float* tW3 = (const float*)d_in[5];
  const float* tb3 = (const float*)d_in[6];
  const float* sW1 = (const float*)d_in[7];
  const float* sb1 = (const float*)d_in[8];
  const float* sW2 = (const float*)d_in[9];
  const float* sb2 = (const float*)d_in[10];
  const float* sW3 = (const float*)d_in[11];
  const float* sb3 = (const float*)d_in[12];
  const float* s_scale = (const float*)d_in[13];
  const float* s_shift = (const float*)d_in[14];
  float* out = (float*)d_out;

  char* ws = (char*)d_ws;
  const size_t W1SZ = (size_t)16 * 512 * 32 * 2;    // 524288
  const size_t W2SZ = (size_t)16 * 512 * 512 * 2;   // 8388608
  u16* W1 = (u16*)(ws);
  u16* W2 = (u16*)(ws + W1SZ);
  u16* W3 = (u16*)(ws + W1SZ + W2SZ);

  cvt_all<<<dim3(288, 1, 16), dim3(32, 8), 0, stream>>>(tW1, sW1, tW2, sW2, tW3, sW3,
                                                        W1, W2, W3);

  meganvp<<<256, 1024, 0, stream>>>(y, W1, W2, W3, tb1, sb1, tb2, sb2, tb3, sb3,
                                    s_scale, s_shift, out);
}

// Round 13
// 509.741 us; speedup vs baseline: 1.1502x; 1.1502x over previous
//
#include <hip/hip_runtime.h>

typedef unsigned short u16;
typedef unsigned int   u32;
typedef _Float16 f16;
typedef __attribute__((ext_vector_type(8))) _Float16 half8;
typedef __attribute__((ext_vector_type(4))) float f32x4;

#define NBATCH 16384

__device__ __forceinline__ u16 f2h(float x) {
  union { f16 h; u16 u; } v; v.h = (f16)x; return v.u;
}

// ---------- prep: transpose fp32 (M x N) -> f16 (N x M), 16 mats (z = layer*2 + net)
// Single launch; blockIdx.x segments: [0,16) W1 | [16,272) W2 | [272,288) W3.
__global__ __launch_bounds__(256) void cvt_all(
    const float* __restrict__ tW1, const float* __restrict__ sW1,
    const float* __restrict__ tW2, const float* __restrict__ sW2,
    const float* __restrict__ tW3, const float* __restrict__ sW3,
    u16* __restrict__ dW1, u16* __restrict__ dW2, u16* __restrict__ dW3)
{
  __shared__ float tile[32][33];
  const int z = blockIdx.z, bx = blockIdx.x;
  const float *tsrc, *ssrc; u16* dst; int M, N, nt, mt;
  if (bx < 16)       { tsrc = tW1; ssrc = sW1; dst = dW1; M = 32;  N = 512; nt = bx;           mt = 0; }
  else if (bx < 272) { tsrc = tW2; ssrc = sW2; dst = dW2; M = 512; N = 512; nt = (bx - 16) & 15; mt = (bx - 16) >> 4; }
  else               { tsrc = tW3; ssrc = sW3; dst = dW3; M = 512; N = 32;  nt = 0;            mt = bx - 272; }
  const float* src = ((z & 1) ? ssrc : tsrc) + (size_t)(z >> 1) * M * N;
  u16* d = dst + (size_t)z * M * N;
  const int n0 = nt * 32, m0 = mt * 32;
  for (int r = 0; r < 4; r++) {
    int m = m0 + threadIdx.y + r * 8, n = n0 + threadIdx.x;
    tile[threadIdx.y + r * 8][threadIdx.x] = src[(size_t)m * N + n];
  }
  __syncthreads();
  for (int r = 0; r < 4; r++) {
    int n = n0 + threadIdx.y + r * 8, m = m0 + threadIdx.x;
    d[(size_t)n * M + m] = f2h(tile[threadIdx.x][threadIdx.y + r * 8]);
  }
}

// ---------- fused RealNVP: 1 block = 64 rows, 512 threads, 8 waves, 256 blocks.
// R13 = R10 (365 us proven: 16x16x32 swapped-operand, b64-packed epilogue,
// depth-3 W2 / depth-4 W3 prefetch LOCAL to their scopes, av/avh ping-pong,
// bias as MFMA C-init, split bufA/bufB) + ONE structural change:
//   HEAD(net0) and H1(net1) run between the same barrier pair (disjoint
//   resources: bufB-read/TS-write vs X-read/bufA-write; bufA freed by bar2).
//   7 -> 6 barriers/layer, and the head's serial ds_read->MFMA chain hides
//   under H1's independent MFMA burst.
// This is R8's merge WITHOUT the live-across-barrier bb/pv hoists that made
// R8 spill (240 MB scratch). All prefetch state stays scope-local.
// Occupancy levers are exhausted: R11 (4 waves/SIMD, same time) and
// R12 (net-parallel 16-wave, clamp+spill) both falsified; 2 waves/SIMD final.
__global__ __launch_bounds__(512, 2) void meganvp(
    const float* __restrict__ y,
    const u16* __restrict__ W1T, const u16* __restrict__ W2T, const u16* __restrict__ W3T,
    const float* __restrict__ tb1, const float* __restrict__ sb1,
    const float* __restrict__ tb2, const float* __restrict__ sb2,
    const float* __restrict__ tb3, const float* __restrict__ sb3,
    const float* __restrict__ s_scale, const float* __restrict__ s_shift,
    float* __restrict__ out)
{
  __shared__ u16 bufA[64 * 512];    // 64 KB: H1 (XOR-swizzled 8-f16 chunks)
  __shared__ u16 bufB[64 * 512];    // 64 KB: H2
  __shared__ u16 X[64 * 40];        // 5 KB: f16 pass-through half
  __shared__ float TS[64 * 68];     // 17 KB: coupling (t,s) pairs, 16B-aligned rows

  const int t = threadIdx.x;
  const int m0 = blockIdx.x * 64;
  const int lane = t & 63, w = t >> 6, lm = lane & 15, quad = lane >> 4;
  const int cw = w * 64;                       // wave's 64-col slice
  const int phase = blockIdx.x & 15;
  const int zr = t >> 3, zq = t & 7, c0 = zq * 8;
  const int hr = (w & 3) * 16, hc = (w >> 2) * 16;   // head tile for this wave

  float z[8], ld[8];
  {
    const float* yb = y + (size_t)(m0 + zr) * 64 + c0;
    f32x4 v0 = *(const f32x4*)&yb[0];
    f32x4 v1 = *(const f32x4*)&yb[4];
#pragma unroll
    for (int k = 0; k < 4; k++) { z[k] = v0[k]; z[4 + k] = v1[k]; }
#pragma unroll
    for (int e = 0; e < 8; e++) ld[e] = 0.f;
  }

  // ---- H1 = relu(X @ W1 + b1), K=32 -> bufA. Swapped mfma: lane holds
  // H1[m = rt*16 + lm, n = cw + ct*16 + quad*4 + g]. Bias as MFMA C-init.
  auto H1L = [&](int layer, int net) {
    const int idx = layer * 2 + net;
    const float* b1p = (net ? sb1 : tb1) + layer * 512 + cw + quad * 4;
    f32x4 bias1[4];
#pragma unroll
    for (int ct = 0; ct < 4; ct++) bias1[ct] = *(const f32x4*)&b1p[ct * 16];
    const u16* W1p = W1T + ((size_t)idx * 512 + cw + lm) * 32 + quad * 8;
    half8 bv[4];
#pragma unroll
    for (int ct = 0; ct < 4; ct++) bv[ct] = *(const half8*)&W1p[ct * 512];
    half8 av[4];
#pragma unroll
    for (int rt = 0; rt < 4; rt++)
      av[rt] = *(const half8*)&X[(rt * 16 + lm) * 40 + quad * 8];
    f32x4 acc[4][4];
#pragma unroll
    for (int rt = 0; rt < 4; rt++)
#pragma unroll
      for (int ct = 0; ct < 4; ct++)
        acc[rt][ct] = __builtin_amdgcn_mfma_f32_16x16x32_f16(bv[ct], av[rt], bias1[ct], 0, 0, 0);
#pragma unroll
    for (int rt = 0; rt < 4; rt++) {
      const int m = rt * 16 + lm;
#pragma unroll
      for (int ct = 0; ct < 4; ct++) {
        const int n0 = cw + ct * 16 + quad * 4;
        union { u16 a[4]; uint2 v; } pk;
#pragma unroll
        for (int g = 0; g < 4; g++) {
          float v = acc[rt][ct][g];
          pk.a[g] = f2h(v > 0.f ? v : 0.f);
        }
        *(uint2*)&bufA[m * 512 + ((((n0 >> 3) ^ (m & 7)) << 3) | (n0 & 7))] = pk.v;
      }
    }
  };

  // ---- H2 = relu(H1 @ W2 + b2), K=512, depth-3 rotating W2 prefetch
  // (scope-local), av ping-pong one iteration ahead. Bias as acc-init.
  auto H2L = [&](int layer, int net) {
    const int idx = layer * 2 + net;
    const float* b2p = (net ? sb2 : tb2) + layer * 512 + cw + quad * 4;
    f32x4 acc[4][4];
#pragma unroll
    for (int ct = 0; ct < 4; ct++) {
      const f32x4 b = *(const f32x4*)&b2p[ct * 16];
#pragma unroll
      for (int rt = 0; rt < 4; rt++) acc[rt][ct] = b;
    }
    const u16* W2p = W2T + ((size_t)idx * 512 + cw + lm) * 512 + quad * 8;
    half8 bb[3][4];                       // depth-3 rotating prefetch (48 VGPR)
#pragma unroll
    for (int p = 0; p < 3; p++) {
      const int kp = ((p + phase) & 15) * 32;
#pragma unroll
      for (int ct = 0; ct < 4; ct++)
        bb[p][ct] = *(const half8*)&W2p[ct * 8192 + kp];
    }
    half8 av[2][4];                       // ping-pong A-frags
    {
      const int kk0 = (phase & 15) * 32;
#pragma unroll
      for (int rt = 0; rt < 4; rt++) {
        const int m = rt * 16 + lm;
        av[0][rt] = *(const half8*)&bufA[m * 512 + ((((kk0 >> 3) + quad) ^ (m & 7)) << 3)];
      }
    }
#pragma unroll
    for (int ci = 0; ci < 16; ci++) {
      if (ci < 15) {                      // prefetch next iter's A-frags
        const int kk1 = ((ci + 1 + phase) & 15) * 32;
#pragma unroll
        for (int rt = 0; rt < 4; rt++) {
          const int m = rt * 16 + lm;
          av[(ci + 1) & 1][rt] = *(const half8*)&bufA[m * 512 + ((((kk1 >> 3) + quad) ^ (m & 7)) << 3)];
        }
      }
#pragma unroll
      for (int rt = 0; rt < 4; rt++)
#pragma unroll
        for (int ct = 0; ct < 4; ct++)
          acc[rt][ct] = __builtin_amdgcn_mfma_f32_16x16x32_f16(bb[ci % 3][ct], av[ci & 1][rt], acc[rt][ct], 0, 0, 0);
      if (ci < 13) {                      // refill consumed W2 slot, 3 ahead
        const int kn = ((ci + 3 + phase) & 15) * 32;
#pragma unroll
        for (int ct = 0; ct < 4; ct++)
          bb[ci % 3][ct] = *(const half8*)&W2p[ct * 8192 + kn];
      }
    }
    // epilogue writes bufB (b64 packed) -> no in-place barrier
#pragma unroll
    for (int rt = 0; rt < 4; rt++) {
      const int m = rt * 16 + lm;
#pragma unroll
      for (int ct = 0; ct < 4; ct++) {
        const int n0 = cw + ct * 16 + quad * 4;
        union { u16 a[4]; uint2 v; } pk;
#pragma unroll
        for (int g = 0; g < 4; g++) {
          float v = acc[rt][ct][g];
          pk.a[g] = f2h(v > 0.f ? v : 0.f);
        }
        *(uint2*)&bufB[m * 512 + ((((n0 >> 3) ^ (m & 7)) << 3) | (n0 & 7))] = pk.v;
      }
    }
  };

  // ---- head: wave w -> rows [hr,+16), col tile hc, K=512. Scope-local
  // depth-4 W3 prefetch + avh ping-pong; b3 as C-init.
  auto HEADL = [&](int layer, int net) {
    const int idx = layer * 2 + net;
    const u16* W3p = W3T + ((size_t)idx * 32 + hc + lm) * 512 + quad * 8;
    const int j0 = hc + quad * 4;
    f32x4 ha[2];
    ha[0] = net ? *(const f32x4*)&sb3[layer * 32 + j0]
                : *(const f32x4*)&tb3[layer * 32 + j0];
    ha[1] = (f32x4){0.f, 0.f, 0.f, 0.f};
    const int m = hr + lm;
    half8 pv[4];                          // depth-4 W3 prefetch
#pragma unroll
    for (int p = 0; p < 4; p++)
      pv[p] = *(const half8*)&W3p[((p + phase) & 15) * 32];
    half8 avh[2];
    {
      const int kk0 = (phase & 15) * 32;
      avh[0] = *(const half8*)&bufB[m * 512 + ((((kk0 >> 3) + quad) ^ (m & 7)) << 3)];
    }
#pragma unroll
    for (int ci = 0; ci < 16; ci++) {
      if (ci < 15) {
        const int kk1 = ((ci + 1 + phase) & 15) * 32;
        avh[(ci + 1) & 1] = *(const half8*)&bufB[m * 512 + ((((kk1 >> 3) + quad) ^ (m & 7)) << 3)];
      }
      ha[ci & 1] = __builtin_amdgcn_mfma_f32_16x16x32_f16(pv[ci & 3], avh[ci & 1], ha[ci & 1], 0, 0, 0);
      if (ci < 12)
        pv[ci & 3] = *(const half8*)&W3p[((ci + 4 + phase) & 15) * 32];
    }
    if (net == 0) {
#pragma unroll
      for (int g = 0; g < 4; g++)
        TS[m * 68 + 2 * (j0 + g)] = ha[0][g] + ha[1][g];
    } else {
      const f32x4 sc = *(const f32x4*)&s_scale[layer * 32 + j0];
      const f32x4 sh = *(const f32x4*)&s_shift[layer * 32 + j0];
#pragma unroll
      for (int g = 0; g < 4; g++)
        TS[m * 68 + 2 * (j0 + g) + 1] = tanhf(ha[0][g] + ha[1][g]) * sc[g] + sh[g];
    }
  };

  for (int layer = 0; layer < 8; layer++) {
    const int par = layer & 1;
    { // X build: 4 pass-through f16 per thread
      union { u16 a[4]; uint2 v; } xv;
#pragma unroll
      for (int e = 0; e < 4; e++) xv.a[e] = f2h(z[2 * e + 1 - par]);
      *(uint2*)&X[zr * 40 + zq * 4] = xv.v;
    }
    __syncthreads();                          // bar0: X visible; fences TS reads

    H1L(layer, 0);                            // X -> bufA(t)
    __syncthreads();                          // bar1: bufA(t) visible

    H2L(layer, 0);                            // bufA(t) -> bufB(t)
    __syncthreads();                          // bar2: bufB(t) visible; bufA free

    HEADL(layer, 0);                          // bufB(t) -> TS even
    H1L(layer, 1);                            // X -> bufA(s)   (no barrier between:
                                              //  disjoint buffers, overlap wanted)
    __syncthreads();                          // bar3: bufA(s) visible; TS(t) done

    H2L(layer, 1);                            // bufA(s) -> bufB(s)
    __syncthreads();                          // bar4: bufB(s) visible

    HEADL(layer, 1);                          // bufB(s) -> TS odd
    __syncthreads();                          // bar5: TS complete

    // ---- coupling: thread reads its 4 (t,s) pairs, updates z/ld in registers.
    // (No trailing barrier: next bar0 orders these TS reads before next writes.)
    {
      const float* base = &TS[zr * 68 + zq * 8];
      f32x4 q0 = *(const f32x4*)&base[0];
      f32x4 q1 = *(const f32x4*)&base[4];
      float q[8];
#pragma unroll
      for (int k = 0; k < 4; k++) { q[k] = q0[k]; q[4 + k] = q1[k]; }
#pragma unroll
      for (int e = 0; e < 4; e++) {
        const float tv = q[2 * e], sv = q[2 * e + 1];
        const int zi = 2 * e + par;
        z[zi] = z[zi] * expf(sv) + tv;
        ld[zi] += sv;
      }
    }
  } // layer

  // ---- store z and log_det
  {
    float* zb = out + (size_t)(m0 + zr) * 64 + c0;
    float* lb = out + (size_t)NBATCH * 64 + (size_t)(m0 + zr) * 64 + c0;
    f32x4 v0, v1, l0, l1;
#pragma unroll
    for (int k = 0; k < 4; k++) {
      v0[k] = z[k]; v1[k] = z[4 + k];
      l0[k] = ld[k]; l1[k] = ld[4 + k];
    }
    *(f32x4*)&zb[0] = v0; *(f32x4*)&zb[4] = v1;
    *(f32x4*)&lb[0] = l0; *(f32x4*)&lb[4] = l1;
  }
}

extern "C" void kernel_launch(void* const* d_in, const int* in_sizes, int n_in,
                              void* d_out, int out_size, void* d_ws, size_t ws_size,
                              hipStream_t stream) {
  (void)in_sizes; (void)n_in; (void)out_size; (void)ws_size;
  const float* y   = (const float*)d_in[0];
  const float* tW1 = (const float*)d_in[1];
  const float* tb1 = (const float*)d_in[2];
  const float* tW2 = (const float*)d_in[3];
  const float* tb2 = (const float*)d_in[4];
  const float* tW3 = (const float*)d_in[5];
  const float* tb3 = (const float*)d_in[6];
  const float* sW1 = (const float*)d_in[7];
  const float* sb1 = (const float*)d_in[8];
  const float* sW2 = (const float*)d_in[9];
  const float* sb2 = (const float*)d_in[10];
  const float* sW3 = (const float*)d_in[11];
  const float* sb3 = (const float*)d_in[12];
  const float* s_scale = (const float*)d_in[13];
  const float* s_shift = (const float*)d_in[14];
  float* out = (float*)d_out;

  char* ws = (char*)d_ws;
  const size_t W1SZ = (size_t)16 * 512 * 32 * 2;    // 524288
  const size_t W2SZ = (size_t)16 * 512 * 512 * 2;   // 8388608
  u16* W1 = (u16*)(ws);
  u16* W2 = (u16*)(ws + W1SZ);
  u16* W3 = (u16*)(ws + W1SZ + W2SZ);

  cvt_all<<<dim3(288, 1, 16), dim3(32, 8), 0, stream>>>(tW1, sW1, tW2, sW2, tW3, sW3,
                                                        W1, W2, W3);

  meganvp<<<256, 512, 0, stream>>>(y, W1, W2, W3, tb1, sb1, tb2, sb2, tb3, sb3,
                                   s_scale, s_shift, out);
}

// Round 14
// 433.364 us; speedup vs baseline: 1.3530x; 1.1762x over previous
//
#include <hip/hip_runtime.h>

typedef unsigned short u16;
typedef unsigned int   u32;
typedef _Float16 f16;
typedef __attribute__((ext_vector_type(8))) _Float16 half8;
typedef __attribute__((ext_vector_type(4))) float f32x4;

#define NBATCH 16384

__device__ __forceinline__ u16 f2h(float x) {
  union { f16 h; u16 u; } v; v.h = (f16)x; return v.u;
}

// ---------- prep: transpose fp32 (M x N) -> f16 (N x M), 16 mats (z = layer*2 + net)
// Single launch; blockIdx.x segments: [0,16) W1 | [16,272) W2 | [272,288) W3.
__global__ __launch_bounds__(256) void cvt_all(
    const float* __restrict__ tW1, const float* __restrict__ sW1,
    const float* __restrict__ tW2, const float* __restrict__ sW2,
    const float* __restrict__ tW3, const float* __restrict__ sW3,
    u16* __restrict__ dW1, u16* __restrict__ dW2, u16* __restrict__ dW3)
{
  __shared__ float tile[32][33];
  const int z = blockIdx.z, bx = blockIdx.x;
  const float *tsrc, *ssrc; u16* dst; int M, N, nt, mt;
  if (bx < 16)       { tsrc = tW1; ssrc = sW1; dst = dW1; M = 32;  N = 512; nt = bx;           mt = 0; }
  else if (bx < 272) { tsrc = tW2; ssrc = sW2; dst = dW2; M = 512; N = 512; nt = (bx - 16) & 15; mt = (bx - 16) >> 4; }
  else               { tsrc = tW3; ssrc = sW3; dst = dW3; M = 512; N = 32;  nt = 0;            mt = bx - 272; }
  const float* src = ((z & 1) ? ssrc : tsrc) + (size_t)(z >> 1) * M * N;
  u16* d = dst + (size_t)z * M * N;
  const int n0 = nt * 32, m0 = mt * 32;
  for (int r = 0; r < 4; r++) {
    int m = m0 + threadIdx.y + r * 8, n = n0 + threadIdx.x;
    tile[threadIdx.y + r * 8][threadIdx.x] = src[(size_t)m * N + n];
  }
  __syncthreads();
  for (int r = 0; r < 4; r++) {
    int n = n0 + threadIdx.y + r * 8, m = m0 + threadIdx.x;
    d[(size_t)n * M + m] = f2h(tile[threadIdx.x][threadIdx.y + r * 8]);
  }
}

// ---------- fused RealNVP: 1 block = 64 rows, 512 threads, 8 waves, 256 blocks.
// FINAL (R10, 365 us meganvp / 435 us e2e, harness-verified round 10):
// 16x16x32 swapped-operand MFMA (lane owns row m, 4 consecutive cols ->
// b64-packed bank-balanced LDS epilogue), depth-3 rotating W2 register
// prefetch, depth-4 W3 prefetch, av/avh one-iter ping-pong, bias folded into
// MFMA C-init, split bufA/bufB, 7 barriers/layer. VGPR 120, zero spill.
// Falsified levers (counter-evidenced): occupancy (R11: 4 waves/SIMD same
// time), 1024-thread packaging (R1/R12: clamp+spill), deeper prefetch
// (R3: spill), 32x32 MFMA (R7: regress), cross-barrier prefetch liveness
// (R9: spill), HEAD||H1 merge (R13: spill). Remaining wall is latency
// serialization of the barrier phase chain at the mandatory 2 waves/SIMD.
__global__ __launch_bounds__(512, 2) void meganvp(
    const float* __restrict__ y,
    const u16* __restrict__ W1T, const u16* __restrict__ W2T, const u16* __restrict__ W3T,
    const float* __restrict__ tb1, const float* __restrict__ sb1,
    const float* __restrict__ tb2, const float* __restrict__ sb2,
    const float* __restrict__ tb3, const float* __restrict__ sb3,
    const float* __restrict__ s_scale, const float* __restrict__ s_shift,
    float* __restrict__ out)
{
  __shared__ u16 bufA[64 * 512];    // 64 KB: H1 (XOR-swizzled 8-f16 chunks)
  __shared__ u16 bufB[64 * 512];    // 64 KB: H2
  __shared__ u16 X[64 * 40];        // 5 KB: f16 pass-through half
  __shared__ float TS[64 * 68];     // 17 KB: coupling (t,s) pairs, 16B-aligned rows

  const int t = threadIdx.x;
  const int m0 = blockIdx.x * 64;
  const int lane = t & 63, w = t >> 6, lm = lane & 15, quad = lane >> 4;
  const int cw = w * 64;                       // wave's 64-col slice
  const int phase = blockIdx.x & 15;
  const int zr = t >> 3, zq = t & 7, c0 = zq * 8;

  float z[8], ld[8];
  {
    const float* yb = y + (size_t)(m0 + zr) * 64 + c0;
    f32x4 v0 = *(const f32x4*)&yb[0];
    f32x4 v1 = *(const f32x4*)&yb[4];
#pragma unroll
    for (int k = 0; k < 4; k++) { z[k] = v0[k]; z[4 + k] = v1[k]; }
#pragma unroll
    for (int e = 0; e < 8; e++) ld[e] = 0.f;
  }

  for (int layer = 0; layer < 8; layer++) {
    const int par = layer & 1;
    { // X build: 4 pass-through f16 per thread
      union { u16 a[4]; uint2 v; } xv;
#pragma unroll
      for (int e = 0; e < 4; e++) xv.a[e] = f2h(z[2 * e + 1 - par]);
      *(uint2*)&X[zr * 40 + zq * 4] = xv.v;
    }
    __syncthreads();                          // bar0: X visible; fences TS reads

    for (int net = 0; net < 2; net++) {
      const int idx = layer * 2 + net;

      // ---- H1 = relu(X @ W1 + b1), K=32, wave cols [cw,+64) -> bufA
      // swapped mfma: lane holds H1[m = rt*16 + lm, n = cw + ct*16 + quad*4 + g]
      // bias as MFMA C-init (rt-invariant).
      {
        const float* b1p = (net ? sb1 : tb1) + layer * 512 + cw + quad * 4;
        f32x4 bias1[4];
#pragma unroll
        for (int ct = 0; ct < 4; ct++) bias1[ct] = *(const f32x4*)&b1p[ct * 16];
        const u16* W1p = W1T + ((size_t)idx * 512 + cw + lm) * 32 + quad * 8;
        half8 bv[4];
#pragma unroll
        for (int ct = 0; ct < 4; ct++) bv[ct] = *(const half8*)&W1p[ct * 512];
        half8 av[4];
#pragma unroll
        for (int rt = 0; rt < 4; rt++)
          av[rt] = *(const half8*)&X[(rt * 16 + lm) * 40 + quad * 8];
        f32x4 acc[4][4];
#pragma unroll
        for (int rt = 0; rt < 4; rt++)
#pragma unroll
          for (int ct = 0; ct < 4; ct++)
            acc[rt][ct] = __builtin_amdgcn_mfma_f32_16x16x32_f16(bv[ct], av[rt], bias1[ct], 0, 0, 0);
        // bufA is free here: prev net's H2 reads completed before its bar2
#pragma unroll
        for (int rt = 0; rt < 4; rt++) {
          const int m = rt * 16 + lm;
#pragma unroll
          for (int ct = 0; ct < 4; ct++) {
            const int n0 = cw + ct * 16 + quad * 4;
            union { u16 a[4]; uint2 v; } pk;
#pragma unroll
            for (int g = 0; g < 4; g++) {
              float v = acc[rt][ct][g];
              pk.a[g] = f2h(v > 0.f ? v : 0.f);
            }
            *(uint2*)&bufA[m * 512 + ((((n0 >> 3) ^ (m & 7)) << 3) | (n0 & 7))] = pk.v;
          }
        }
      }
      __syncthreads();                        // bar1: H1 written -> H2 reads

      // ---- H2 = relu(H1 @ W2 + b2), K=512, depth-3 rotating W2 prefetch,
      //      av ping-pong one iteration ahead. Bias as acc-init.
      {
        const float* b2p = (net ? sb2 : tb2) + layer * 512 + cw + quad * 4;
        f32x4 acc[4][4];
#pragma unroll
        for (int ct = 0; ct < 4; ct++) {
          const f32x4 b = *(const f32x4*)&b2p[ct * 16];
#pragma unroll
          for (int rt = 0; rt < 4; rt++) acc[rt][ct] = b;
        }
        const u16* W2p = W2T + ((size_t)idx * 512 + cw + lm) * 512 + quad * 8;
        half8 bb[3][4];                       // depth-3 rotating prefetch (48 VGPR)
#pragma unroll
        for (int p = 0; p < 3; p++) {
          const int kp = ((p + phase) & 15) * 32;
#pragma unroll
          for (int ct = 0; ct < 4; ct++)
            bb[p][ct] = *(const half8*)&W2p[ct * 8192 + kp];
        }
        half8 av[2][4];                       // ping-pong A-frags
        {
          const int kk0 = (phase & 15) * 32;
#pragma unroll
          for (int rt = 0; rt < 4; rt++) {
            const int m = rt * 16 + lm;
            av[0][rt] = *(const half8*)&bufA[m * 512 + ((((kk0 >> 3) + quad) ^ (m & 7)) << 3)];
          }
        }
#pragma unroll
        for (int ci = 0; ci < 16; ci++) {
          if (ci < 15) {                      // prefetch next iter's A-frags
            const int kk1 = ((ci + 1 + phase) & 15) * 32;
#pragma unroll
            for (int rt = 0; rt < 4; rt++) {
              const int m = rt * 16 + lm;
              av[(ci + 1) & 1][rt] = *(const half8*)&bufA[m * 512 + ((((kk1 >> 3) + quad) ^ (m & 7)) << 3)];
            }
          }
#pragma unroll
          for (int rt = 0; rt < 4; rt++)
#pragma unroll
            for (int ct = 0; ct < 4; ct++)
              acc[rt][ct] = __builtin_amdgcn_mfma_f32_16x16x32_f16(bb[ci % 3][ct], av[ci & 1][rt], acc[rt][ct], 0, 0, 0);
          if (ci < 13) {                      // refill consumed W2 slot, 3 ahead
            const int kn = ((ci + 3 + phase) & 15) * 32;
#pragma unroll
            for (int ct = 0; ct < 4; ct++)
              bb[ci % 3][ct] = *(const half8*)&W2p[ct * 8192 + kn];
          }
        }
        // epilogue writes bufB (b64 packed) -> no in-place barrier
#pragma unroll
        for (int rt = 0; rt < 4; rt++) {
          const int m = rt * 16 + lm;
#pragma unroll
          for (int ct = 0; ct < 4; ct++) {
            const int n0 = cw + ct * 16 + quad * 4;
            union { u16 a[4]; uint2 v; } pk;
#pragma unroll
            for (int g = 0; g < 4; g++) {
              float v = acc[rt][ct][g];
              pk.a[g] = f2h(v > 0.f ? v : 0.f);
            }
            *(uint2*)&bufB[m * 512 + ((((n0 >> 3) ^ (m & 7)) << 3) | (n0 & 7))] = pk.v;
          }
        }
      }
      __syncthreads();                        // bar2: bufB visible; bufA reads all done

      // ---- head: wave w -> rows [(w&3)*16,+16), col tile (w>>2)*16, K=512
      // swapped mfma: lane holds out[m = hr + lm, j = hc + quad*4 + g]
      // depth-4 W3 prefetch + avh ping-pong; b3 as C-init.
      {
        const int hr = (w & 3) * 16, hc = (w >> 2) * 16;
        const u16* W3p = W3T + ((size_t)idx * 32 + hc + lm) * 512 + quad * 8;
        const int j0 = hc + quad * 4;
        f32x4 ha[2];
        ha[0] = net ? *(const f32x4*)&sb3[layer * 32 + j0]
                    : *(const f32x4*)&tb3[layer * 32 + j0];
        ha[1] = (f32x4){0.f, 0.f, 0.f, 0.f};
        const int m = hr + lm;
        half8 pv[4];                          // depth-4 W3 prefetch
#pragma unroll
        for (int p = 0; p < 4; p++)
          pv[p] = *(const half8*)&W3p[((p + phase) & 15) * 32];
        half8 avh[2];
        {
          const int kk0 = (phase & 15) * 32;
          avh[0] = *(const half8*)&bufB[m * 512 + ((((kk0 >> 3) + quad) ^ (m & 7)) << 3)];
        }
#pragma unroll
        for (int ci = 0; ci < 16; ci++) {
          if (ci < 15) {
            const int kk1 = ((ci + 1 + phase) & 15) * 32;
            avh[(ci + 1) & 1] = *(const half8*)&bufB[m * 512 + ((((kk1 >> 3) + quad) ^ (m & 7)) << 3)];
          }
          ha[ci & 1] = __builtin_amdgcn_mfma_f32_16x16x32_f16(pv[ci & 3], avh[ci & 1], ha[ci & 1], 0, 0, 0);
          if (ci < 12)
            pv[ci & 3] = *(const half8*)&W3p[((ci + 4 + phase) & 15) * 32];
        }
        if (net == 0) {
#pragma unroll
          for (int g = 0; g < 4; g++)
            TS[m * 68 + 2 * (j0 + g)] = ha[0][g] + ha[1][g];
        } else {
          const f32x4 sc = *(const f32x4*)&s_scale[layer * 32 + j0];
          const f32x4 sh = *(const f32x4*)&s_shift[layer * 32 + j0];
#pragma unroll
          for (int g = 0; g < 4; g++)
            TS[m * 68 + 2 * (j0 + g) + 1] = tanhf(ha[0][g] + ha[1][g]) * sc[g] + sh[g];
        }
      }
      __syncthreads();                        // bar3: bufB reads done; TS visible
    } // net

    // ---- coupling: thread reads its 4 (t,s) pairs, updates z/ld in registers.
    // (No trailing barrier: next bar0 orders these TS reads before the next
    //  head's TS writes.)
    {
      const float* base = &TS[zr * 68 + zq * 8];
      f32x4 q0 = *(const f32x4*)&base[0];
      f32x4 q1 = *(const f32x4*)&base[4];
      float q[8];
#pragma unroll
      for (int k = 0; k < 4; k++) { q[k] = q0[k]; q[4 + k] = q1[k]; }
#pragma unroll
      for (int e = 0; e < 4; e++) {
        const float tv = q[2 * e], sv = q[2 * e + 1];
        const int zi = 2 * e + par;
        z[zi] = z[zi] * expf(sv) + tv;
        ld[zi] += sv;
      }
    }
  } // layer

  // ---- store z and log_det
  {
    float* zb = out + (size_t)(m0 + zr) * 64 + c0;
    float* lb = out + (size_t)NBATCH * 64 + (size_t)(m0 + zr) * 64 + c0;
    f32x4 v0, v1, l0, l1;
#pragma unroll
    for (int k = 0; k < 4; k++) {
      v0[k] = z[k]; v1[k] = z[4 + k];
      l0[k] = ld[k]; l1[k] = ld[4 + k];
    }
    *(f32x4*)&zb[0] = v0; *(f32x4*)&zb[4] = v1;
    *(f32x4*)&lb[0] = l0; *(f32x4*)&lb[4] = l1;
  }
}

extern "C" void kernel_launch(void* const* d_in, const int* in_sizes, int n_in,
                              void* d_out, int out_size, void* d_ws, size_t ws_size,
                              hipStream_t stream) {
  (void)in_sizes; (void)n_in; (void)out_size; (void)ws_size;
  const float* y   = (const float*)d_in[0];
  const float* tW1 = (const float*)d_in[1];
  const float* tb1 = (const float*)d_in[2];
  const float* tW2 = (const float*)d_in[3];
  const float* tb2 = (const float*)d_in[4];
  const float* tW3 = (const float*)d_in[5];
  const float* tb3 = (const float*)d_in[6];
  const float* sW1 = (const float*)d_in[7];
  const float* sb1 = (const float*)d_in[8];
  const float* sW2 = (const float*)d_in[9];
  const float* sb2 = (const float*)d_in[10];
  const float* sW3 = (const float*)d_in[11];
  const float* sb3 = (const float*)d_in[12];
  const float* s_scale = (const float*)d_in[13];
  const float* s_shift = (const float*)d_in[14];
  float* out = (float*)d_out;

  char* ws = (char*)d_ws;
  const size_t W1SZ = (size_t)16 * 512 * 32 * 2;    // 524288
  const size_t W2SZ = (size_t)16 * 512 * 512 * 2;   // 8388608
  u16* W1 = (u16*)(ws);
  u16* W2 = (u16*)(ws + W1SZ);
  u16* W3 = (u16*)(ws + W1SZ + W2SZ);

  cvt_all<<<dim3(288, 1, 16), dim3(32, 8), 0, stream>>>(tW1, sW1, tW2, sW2, tW3, sW3,
                                                        W1, W2, W3);

  meganvp<<<256, 512, 0, stream>>>(y, W1, W2, W3, tb1, sb1, tb2, sb2, tb3, sb3,
                                   s_scale, s_shift, out);
}

// Round 15
// 431.732 us; speedup vs baseline: 1.3581x; 1.0038x over previous
//
#include <hip/hip_runtime.h>

typedef unsigned short u16;
typedef unsigned int   u32;
typedef _Float16 f16;
typedef __attribute__((ext_vector_type(8))) _Float16 half8;
typedef __attribute__((ext_vector_type(4))) float f32x4;

#define NBATCH 16384

__device__ __forceinline__ u16 f2h(float x) {
  union { f16 h; u16 u; } v; v.h = (f16)x; return v.u;
}

// ---------- prep: transpose fp32 (M x N) -> f16 (N x M), 16 mats (z = layer*2 + net)
// Single launch; blockIdx.x segments: [0,16) W1 | [16,272) W2 | [272,288) W3.
// R15: vectorized — read one float4/thread (was 4 scalar dwords), write one
// uint2 (4 packed f16 along m, 64 B contiguous per 8 lanes) instead of 4
// scalar 2-byte stores. LDS tile[32][33] bank-checked <=2-way both phases.
__global__ __launch_bounds__(256) void cvt_all(
    const float* __restrict__ tW1, const float* __restrict__ sW1,
    const float* __restrict__ tW2, const float* __restrict__ sW2,
    const float* __restrict__ tW3, const float* __restrict__ sW3,
    u16* __restrict__ dW1, u16* __restrict__ dW2, u16* __restrict__ dW3)
{
  __shared__ float tile[32][33];
  const int z = blockIdx.z, bx = blockIdx.x;
  const float *tsrc, *ssrc; u16* dst; int M, N, nt, mt;
  if (bx < 16)       { tsrc = tW1; ssrc = sW1; dst = dW1; M = 32;  N = 512; nt = bx;           mt = 0; }
  else if (bx < 272) { tsrc = tW2; ssrc = sW2; dst = dW2; M = 512; N = 512; nt = (bx - 16) & 15; mt = (bx - 16) >> 4; }
  else               { tsrc = tW3; ssrc = sW3; dst = dW3; M = 512; N = 32;  nt = 0;            mt = bx - 272; }
  const float* src = ((z & 1) ? ssrc : tsrc) + (size_t)(z >> 1) * M * N;
  u16* d = dst + (size_t)z * M * N;
  const int n0 = nt * 32, m0 = mt * 32;
  const int tt = threadIdx.y * 32 + threadIdx.x;
  {
    const int mr = tt >> 3, nc = (tt & 7) * 4;   // 16B-aligned: N,n0 mult-32, nc mult-4
    f32x4 v = *(const f32x4*)&src[(size_t)(m0 + mr) * N + n0 + nc];
#pragma unroll
    for (int j = 0; j < 4; j++) tile[mr][nc + j] = v[j];
  }
  __syncthreads();
  {
    const int nn = tt >> 3, mc = (tt & 7) * 4;   // 8B-aligned: M mult-32, mc mult-4
    union { u16 a[4]; uint2 v; } pk;
#pragma unroll
    for (int j = 0; j < 4; j++) pk.a[j] = f2h(tile[mc + j][nn]);
    *(uint2*)&d[(size_t)(n0 + nn) * M + m0 + mc] = pk.v;
  }
}

// ---------- fused RealNVP: 1 block = 64 rows, 512 threads, 8 waves, 256 blocks.
// FINAL meganvp (R10/R14, 373 us verified twice; byte-identical here):
// 16x16x32 swapped-operand MFMA (lane owns row m, 4 consecutive cols ->
// b64-packed bank-balanced LDS epilogue), depth-3 rotating W2 register
// prefetch, depth-4 W3 prefetch, av/avh one-iter ping-pong, bias folded into
// MFMA C-init, split bufA/bufB, 7 barriers/layer. VGPR 120, zero spill.
// Falsified levers (counter-evidenced): occupancy (R11: 4 waves/SIMD same
// time), 1024-thread packaging (R1/R12: clamp+spill), deeper prefetch
// (R3: spill), 32x32 MFMA (R7: regress), cross-barrier prefetch liveness
// (R9: spill), HEAD||H1 merge (R13: spill). Remaining wall is latency
// serialization of the barrier phase chain at the mandatory 2 waves/SIMD.
__global__ __launch_bounds__(512, 2) void meganvp(
    const float* __restrict__ y,
    const u16* __restrict__ W1T, const u16* __restrict__ W2T, const u16* __restrict__ W3T,
    const float* __restrict__ tb1, const float* __restrict__ sb1,
    const float* __restrict__ tb2, const float* __restrict__ sb2,
    const float* __restrict__ tb3, const float* __restrict__ sb3,
    const float* __restrict__ s_scale, const float* __restrict__ s_shift,
    float* __restrict__ out)
{
  __shared__ u16 bufA[64 * 512];    // 64 KB: H1 (XOR-swizzled 8-f16 chunks)
  __shared__ u16 bufB[64 * 512];    // 64 KB: H2
  __shared__ u16 X[64 * 40];        // 5 KB: f16 pass-through half
  __shared__ float TS[64 * 68];     // 17 KB: coupling (t,s) pairs, 16B-aligned rows

  const int t = threadIdx.x;
  const int m0 = blockIdx.x * 64;
  const int lane = t & 63, w = t >> 6, lm = lane & 15, quad = lane >> 4;
  const int cw = w * 64;                       // wave's 64-col slice
  const int phase = blockIdx.x & 15;
  const int zr = t >> 3, zq = t & 7, c0 = zq * 8;

  float z[8], ld[8];
  {
    const float* yb = y + (size_t)(m0 + zr) * 64 + c0;
    f32x4 v0 = *(const f32x4*)&yb[0];
    f32x4 v1 = *(const f32x4*)&yb[4];
#pragma unroll
    for (int k = 0; k < 4; k++) { z[k] = v0[k]; z[4 + k] = v1[k]; }
#pragma unroll
    for (int e = 0; e < 8; e++) ld[e] = 0.f;
  }

  for (int layer = 0; layer < 8; layer++) {
    const int par = layer & 1;
    { // X build: 4 pass-through f16 per thread
      union { u16 a[4]; uint2 v; } xv;
#pragma unroll
      for (int e = 0; e < 4; e++) xv.a[e] = f2h(z[2 * e + 1 - par]);
      *(uint2*)&X[zr * 40 + zq * 4] = xv.v;
    }
    __syncthreads();                          // bar0: X visible; fences TS reads

    for (int net = 0; net < 2; net++) {
      const int idx = layer * 2 + net;

      // ---- H1 = relu(X @ W1 + b1), K=32, wave cols [cw,+64) -> bufA
      // swapped mfma: lane holds H1[m = rt*16 + lm, n = cw + ct*16 + quad*4 + g]
      // bias as MFMA C-init (rt-invariant).
      {
        const float* b1p = (net ? sb1 : tb1) + layer * 512 + cw + quad * 4;
        f32x4 bias1[4];
#pragma unroll
        for (int ct = 0; ct < 4; ct++) bias1[ct] = *(const f32x4*)&b1p[ct * 16];
        const u16* W1p = W1T + ((size_t)idx * 512 + cw + lm) * 32 + quad * 8;
        half8 bv[4];
#pragma unroll
        for (int ct = 0; ct < 4; ct++) bv[ct] = *(const half8*)&W1p[ct * 512];
        half8 av[4];
#pragma unroll
        for (int rt = 0; rt < 4; rt++)
          av[rt] = *(const half8*)&X[(rt * 16 + lm) * 40 + quad * 8];
        f32x4 acc[4][4];
#pragma unroll
        for (int rt = 0; rt < 4; rt++)
#pragma unroll
          for (int ct = 0; ct < 4; ct++)
            acc[rt][ct] = __builtin_amdgcn_mfma_f32_16x16x32_f16(bv[ct], av[rt], bias1[ct], 0, 0, 0);
        // bufA is free here: prev net's H2 reads completed before its bar2
#pragma unroll
        for (int rt = 0; rt < 4; rt++) {
          const int m = rt * 16 + lm;
#pragma unroll
          for (int ct = 0; ct < 4; ct++) {
            const int n0 = cw + ct * 16 + quad * 4;
            union { u16 a[4]; uint2 v; } pk;
#pragma unroll
            for (int g = 0; g < 4; g++) {
              float v = acc[rt][ct][g];
              pk.a[g] = f2h(v > 0.f ? v : 0.f);
            }
            *(uint2*)&bufA[m * 512 + ((((n0 >> 3) ^ (m & 7)) << 3) | (n0 & 7))] = pk.v;
          }
        }
      }
      __syncthreads();                        // bar1: H1 written -> H2 reads

      // ---- H2 = relu(H1 @ W2 + b2), K=512, depth-3 rotating W2 prefetch,
      //      av ping-pong one iteration ahead. Bias as acc-init.
      {
        const float* b2p = (net ? sb2 : tb2) + layer * 512 + cw + quad * 4;
        f32x4 acc[4][4];
#pragma unroll
        for (int ct = 0; ct < 4; ct++) {
          const f32x4 b = *(const f32x4*)&b2p[ct * 16];
#pragma unroll
          for (int rt = 0; rt < 4; rt++) acc[rt][ct] = b;
        }
        const u16* W2p = W2T + ((size_t)idx * 512 + cw + lm) * 512 + quad * 8;
        half8 bb[3][4];                       // depth-3 rotating prefetch (48 VGPR)
#pragma unroll
        for (int p = 0; p < 3; p++) {
          const int kp = ((p + phase) & 15) * 32;
#pragma unroll
          for (int ct = 0; ct < 4; ct++)
            bb[p][ct] = *(const half8*)&W2p[ct * 8192 + kp];
        }
        half8 av[2][4];                       // ping-pong A-frags
        {
          const int kk0 = (phase & 15) * 32;
#pragma unroll
          for (int rt = 0; rt < 4; rt++) {
            const int m = rt * 16 + lm;
            av[0][rt] = *(const half8*)&bufA[m * 512 + ((((kk0 >> 3) + quad) ^ (m & 7)) << 3)];
          }
        }
#pragma unroll
        for (int ci = 0; ci < 16; ci++) {
          if (ci < 15) {                      // prefetch next iter's A-frags
            const int kk1 = ((ci + 1 + phase) & 15) * 32;
#pragma unroll
            for (int rt = 0; rt < 4; rt++) {
              const int m = rt * 16 + lm;
              av[(ci + 1) & 1][rt] = *(const half8*)&bufA[m * 512 + ((((kk1 >> 3) + quad) ^ (m & 7)) << 3)];
            }
          }
#pragma unroll
          for (int rt = 0; rt < 4; rt++)
#pragma unroll
            for (int ct = 0; ct < 4; ct++)
              acc[rt][ct] = __builtin_amdgcn_mfma_f32_16x16x32_f16(bb[ci % 3][ct], av[ci & 1][rt], acc[rt][ct], 0, 0, 0);
          if (ci < 13) {                      // refill consumed W2 slot, 3 ahead
            const int kn = ((ci + 3 + phase) & 15) * 32;
#pragma unroll
            for (int ct = 0; ct < 4; ct++)
              bb[ci % 3][ct] = *(const half8*)&W2p[ct * 8192 + kn];
          }
        }
        // epilogue writes bufB (b64 packed) -> no in-place barrier
#pragma unroll
        for (int rt = 0; rt < 4; rt++) {
          const int m = rt * 16 + lm;
#pragma unroll
          for (int ct = 0; ct < 4; ct++) {
            const int n0 = cw + ct * 16 + quad * 4;
            union { u16 a[4]; uint2 v; } pk;
#pragma unroll
            for (int g = 0; g < 4; g++) {
              float v = acc[rt][ct][g];
              pk.a[g] = f2h(v > 0.f ? v : 0.f);
            }
            *(uint2*)&bufB[m * 512 + ((((n0 >> 3) ^ (m & 7)) << 3) | (n0 & 7))] = pk.v;
          }
        }
      }
      __syncthreads();                        // bar2: bufB visible; bufA reads all done

      // ---- head: wave w -> rows [(w&3)*16,+16), col tile (w>>2)*16, K=512
      // swapped mfma: lane holds out[m = hr + lm, j = hc + quad*4 + g]
      // depth-4 W3 prefetch + avh ping-pong; b3 as C-init.
      {
        const int hr = (w & 3) * 16, hc = (w >> 2) * 16;
        const u16* W3p = W3T + ((size_t)idx * 32 + hc + lm) * 512 + quad * 8;
        const int j0 = hc + quad * 4;
        f32x4 ha[2];
        ha[0] = net ? *(const f32x4*)&sb3[layer * 32 + j0]
                    : *(const f32x4*)&tb3[layer * 32 + j0];
        ha[1] = (f32x4){0.f, 0.f, 0.f, 0.f};
        const int m = hr + lm;
        half8 pv[4];                          // depth-4 W3 prefetch
#pragma unroll
        for (int p = 0; p < 4; p++)
          pv[p] = *(const half8*)&W3p[((p + phase) & 15) * 32];
        half8 avh[2];
        {
          const int kk0 = (phase & 15) * 32;
          avh[0] = *(const half8*)&bufB[m * 512 + ((((kk0 >> 3) + quad) ^ (m & 7)) << 3)];
        }
#pragma unroll
        for (int ci = 0; ci < 16; ci++) {
          if (ci < 15) {
            const int kk1 = ((ci + 1 + phase) & 15) * 32;
            avh[(ci + 1) & 1] = *(const half8*)&bufB[m * 512 + ((((kk1 >> 3) + quad) ^ (m & 7)) << 3)];
          }
          ha[ci & 1] = __builtin_amdgcn_mfma_f32_16x16x32_f16(pv[ci & 3], avh[ci & 1], ha[ci & 1], 0, 0, 0);
          if (ci < 12)
            pv[ci & 3] = *(const half8*)&W3p[((ci + 4 + phase) & 15) * 32];
        }
        if (net == 0) {
#pragma unroll
          for (int g = 0; g < 4; g++)
            TS[m * 68 + 2 * (j0 + g)] = ha[0][g] + ha[1][g];
        } else {
          const f32x4 sc = *(const f32x4*)&s_scale[layer * 32 + j0];
          const f32x4 sh = *(const f32x4*)&s_shift[layer * 32 + j0];
#pragma unroll
          for (int g = 0; g < 4; g++)
            TS[m * 68 + 2 * (j0 + g) + 1] = tanhf(ha[0][g] + ha[1][g]) * sc[g] + sh[g];
        }
      }
      __syncthreads();                        // bar3: bufB reads done; TS visible
    } // net

    // ---- coupling: thread reads its 4 (t,s) pairs, updates z/ld in registers.
    // (No trailing barrier: next bar0 orders these TS reads before the next
    //  head's TS writes.)
    {
      const float* base = &TS[zr * 68 + zq * 8];
      f32x4 q0 = *(const f32x4*)&base[0];
      f32x4 q1 = *(const f32x4*)&base[4];
      float q[8];
#pragma unroll
      for (int k = 0; k < 4; k++) { q[k] = q0[k]; q[4 + k] = q1[k]; }
#pragma unroll
      for (int e = 0; e < 4; e++) {
        const float tv = q[2 * e], sv = q[2 * e + 1];
        const int zi = 2 * e + par;
        z[zi] = z[zi] * expf(sv) + tv;
        ld[zi] += sv;
      }
    }
  } // layer

  // ---- store z and log_det
  {
    float* zb = out + (size_t)(m0 + zr) * 64 + c0;
    float* lb = out + (size_t)NBATCH * 64 + (size_t)(m0 + zr) * 64 + c0;
    f32x4 v0, v1, l0, l1;
#pragma unroll
    for (int k = 0; k < 4; k++) {
      v0[k] = z[k]; v1[k] = z[4 + k];
      l0[k] = ld[k]; l1[k] = ld[4 + k];
    }
    *(f32x4*)&zb[0] = v0; *(f32x4*)&zb[4] = v1;
    *(f32x4*)&lb[0] = l0; *(f32x4*)&lb[4] = l1;
  }
}

extern "C" void kernel_launch(void* const* d_in, const int* in_sizes, int n_in,
                              void* d_out, int out_size, void* d_ws, size_t ws_size,
                              hipStream_t stream) {
  (void)in_sizes; (void)n_in; (void)out_size; (void)ws_size;
  const float* y   = (const float*)d_in[0];
  const float* tW1 = (const float*)d_in[1];
  const float* tb1 = (const float*)d_in[2];
  const float* tW2 = (const float*)d_in[3];
  const float* tb2 = (const float*)d_in[4];
  const float* tW3 = (const float*)d_in[5];
  const float* tb3 = (const float*)d_in[6];
  const float* sW1 = (const float*)d_in[7];
  const float* sb1 = (const float*)d_in[8];
  const float* sW2 = (const float*)d_in[9];
  const float* sb2 = (const float*)d_in[10];
  const float* sW3 = (const float*)d_in[11];
  const float* sb3 = (const float*)d_in[12];
  const float* s_scale = (const float*)d_in[13];
  const float* s_shift = (const float*)d_in[14];
  float* out = (float*)d_out;

  char* ws = (char*)d_ws;
  const size_t W1SZ = (size_t)16 * 512 * 32 * 2;    // 524288
  const size_t W2SZ = (size_t)16 * 512 * 512 * 2;   // 8388608
  u16* W1 = (u16*)(ws);
  u16* W2 = (u16*)(ws + W1SZ);
  u16* W3 = (u16*)(ws + W1SZ + W2SZ);

  cvt_all<<<dim3(288, 1, 16), dim3(32, 8), 0, stream>>>(tW1, sW1, tW2, sW2, tW3, sW3,
                                                        W1, W2, W3);

  meganvp<<<256, 512, 0, stream>>>(y, W1, W2, W3, tb1, sb1, tb2, sb2, tb3, sb3,
                                   s_scale, s_shift, out);
}